// Round 11
// baseline (7967.268 us; speedup 1.0000x reference)
//
#include <hip/hip_runtime.h>
#include <stdint.h>

typedef unsigned long long u64;
typedef uint32_t u32;

#define VOCAB 128
#define RD 128
#define DM 1024
#define NFF 6
#define BATCH 64
#define TSTEPS 512
#define NLOC 3    // layers per pipeline stage (2 in regs + 1 in LDS)
#define THR 512   // threads per block; thread owns cols tid and tid+512

// ---------------------------------------------------------------------------
// ws layout (bytes):
//   [0,        786432)  ffbits [L][w][j] u64  (L<6, w<16, j<1024)
//   [786432,  +2048)    ebits  [v][2]    u64
//   [788480,  +2048)    headb  [v][2]    u64
//   [790528,  +512)     losses [64]      double
//   [791040,  +8192)    xbuf   [64][16]  u64  (x for next step, written by B)
//   [799232,  +8192)    mbuf   [64][16]  u64  (mid h after layer 2, by A)
//   [807424,  +256)     fA     [64]      u32
//   [807680,  +256)     fB     [64]      u32
// ---------------------------------------------------------------------------
#define OFF_EB    786432
#define OFF_HB    788480
#define OFF_LOSS  790528
#define OFF_XBUF  791040
#define OFF_MBUF  799232
#define OFF_FA    807424
#define OFF_FB    807680

__device__ __forceinline__ void wait_ge(const u32* f, u32 target) {
    while (__hip_atomic_load(f, __ATOMIC_ACQUIRE, __HIP_MEMORY_SCOPE_AGENT) < target)
        __builtin_amdgcn_s_sleep(1);
}

// Pack ff sign bits: bit b of word (L,w,j) = (ff[L][w*64+b][j] < 0)  (1 => -1)
__global__ void pack_ff(const float* __restrict__ ff, u64* __restrict__ ffb) {
    int wid  = blockIdx.x * (blockDim.x >> 6) + (threadIdx.x >> 6); // 0..1535
    int lane = threadIdx.x & 63;
    int jt = wid & 15;
    int w  = (wid >> 4) & 15;
    int i  = wid >> 8;
    int j  = jt * 64 + lane;
    const float* src = ff + ((size_t)(i * DM) + w * 64) * DM + j;
    u64 word = 0;
#pragma unroll
    for (int b = 0; b < 64; ++b) {
        float v = src[(size_t)b * DM];
        word |= (u64)(v < 0.0f) << b;
    }
    ffb[((i * 16 + w) << 10) + j] = word;
}

__global__ void pack_small(const float* __restrict__ emb, const float* __restrict__ head,
                           u64* __restrict__ eb, u64* __restrict__ hb) {
    int tid = threadIdx.x; // 0..255
    if (tid < 128) {
        int v = tid;
        for (int wd = 0; wd < 2; ++wd) {
            u64 word = 0;
            for (int l = 0; l < 64; ++l)
                word |= (u64)(emb[v * RD + wd * 64 + l] < 0.0f) << l;
            eb[v * 2 + wd] = word;
        }
    } else {
        int v = tid - 128;
        for (int wd = 0; wd < 2; ++wd) {
            u64 word = 0;
            for (int l = 0; l < 64; ++l)
                word |= (u64)(head[(wd * 64 + l) * VOCAB + v] < 0.0f) << l;
            hb[v * 2 + wd] = word;
        }
    }
}

// Register-layer pass: weights fr[L][c][w] (L literal). Thread's cols:
// c=0 -> tid (ballot word wv), c=1 -> tid+512 (ballot word 8+wv).
#define REG_PASS(P, L, EMIT) do {                                               \
    const ulonglong2* hp_ = (const ulonglong2*)hx[P];                           \
    int a0_ = 0, a1_ = 0;                                                       \
    _Pragma("unroll")                                                           \
    for (int q_ = 0; q_ < 8; ++q_) {                                            \
        ulonglong2 hv_ = hp_[q_]; /* broadcast ds_read_b128 */                  \
        a0_ += __popcll(hv_.x ^ fr[L][0][2*q_]) + __popcll(hv_.y ^ fr[L][0][2*q_+1]); \
        a1_ += __popcll(hv_.x ^ fr[L][1][2*q_]) + __popcll(hv_.y ^ fr[L][1][2*q_+1]); \
    }                                                                           \
    u64 m0_ = __ballot(a0_ >= cthr[L][0]);                                      \
    u64 m1_ = __ballot(a1_ >= cthr[L][1]);                                      \
    EMIT;                                                                       \
    __syncthreads();                                                            \
} while (0)

// LDS-layer pass (local layer 2): weights in wlds, conflict-free b128 reads.
#define LDS_PASS(P, EMIT) do {                                                  \
    const ulonglong2* hp_ = (const ulonglong2*)hx[P];                           \
    int a0_ = 0, a1_ = 0;                                                       \
    _Pragma("unroll")                                                           \
    for (int q_ = 0; q_ < 8; ++q_) {                                            \
        ulonglong2 hv_ = hp_[q_];                                               \
        ulonglong2 w0_ = *(const ulonglong2*)wlds[q_][tid];                     \
        ulonglong2 w1_ = *(const ulonglong2*)wlds[q_][512 + tid];               \
        a0_ += __popcll(hv_.x ^ w0_.x) + __popcll(hv_.y ^ w0_.y);               \
        a1_ += __popcll(hv_.x ^ w1_.x) + __popcll(hv_.y ^ w1_.y);               \
    }                                                                           \
    u64 m0_ = __ballot(a0_ >= cthr[2][0]);                                      \
    u64 m1_ = __ballot(a1_ >= cthr[2][1]);                                      \
    EMIT;                                                                       \
    __syncthreads();                                                            \
} while (0)

// Pipelined main kernel: 64 blocks x 512 threads, 1 block/CU (133 KB LDS),
// 2 waves/SIMD -> 256-reg budget. Per-thread residency: 2 layers x 2 cols x
// 16 u64 = 128 regs; third layer in LDS (128 KB). Zero steady-state weight
// memory traffic. Blocks 0..31 = stage A (layers 0-2) for rows {2g,2g+1};
// blocks 32..63 = stage B (layers 3-5 + head). Pair (g,g+32) shares an XCD.
__global__ void
__attribute__((amdgpu_flat_work_group_size(THR, THR), amdgpu_waves_per_eu(1, 2)))
brnn_pipe(const int* __restrict__ tokens,
          const float* __restrict__ initial_lat,
          const float* __restrict__ thr_lat,
          const u64* __restrict__ ffb,
          const u64* __restrict__ eb,
          const u64* __restrict__ hb,
          u64* __restrict__ xbuf, u64* __restrict__ mbuf,
          u32* __restrict__ fA, u32* __restrict__ fB,
          double* __restrict__ losses)
{
    const int blk  = blockIdx.x;
    const int role = blk >> 5; // 0 = A, 1 = B
    const int g    = blk & 31;
    const int tid  = threadIdx.x;
    const int lane = tid & 63;
    const int wv   = tid >> 6; // 0..7

    __shared__ __align__(16) u64 wlds[8][1024][2]; // local layer 2: 128 KB
    __shared__ __align__(16) u64 hx[2][16];
    __shared__ u64 hbL[2 * VOCAB];

    const int lbase = role * NLOC;

    // --- fill LDS-resident third layer (lbase+2) ---
#pragma unroll
    for (int wp = 0; wp < 8; ++wp)
#pragma unroll
        for (int c = 0; c < 2; ++c) {
            int j = c * THR + tid;
            u64 lo = ffb[(((lbase + 2) * 16 + 2 * wp)     << 10) + j];
            u64 hi = ffb[(((lbase + 2) * 16 + 2 * wp + 1) << 10) + j];
            wlds[wp][j][0] = lo;
            wlds[wp][j][1] = hi;
        }

    // --- register-resident layers lbase+0, lbase+1: 128 regs ---
    u64 fr[2][2][16];
#pragma unroll
    for (int l = 0; l < 2; ++l)
#pragma unroll
        for (int c = 0; c < 2; ++c)
#pragma unroll
            for (int w = 0; w < 16; ++w)
                fr[l][c][w] = ffb[(((lbase + l) * 16 + w) << 10) + c * THR + tid];

    // thresholds -> popcount cutoffs:  bit(-1) <=> popcnt >= cthr
    int cthr[NLOC][2];
#pragma unroll
    for (int l = 0; l < NLOC; ++l)
#pragma unroll
        for (int c = 0; c < 2; ++c) {
            int th = (int)rintf(thr_lat[(lbase + l) * DM + c * THR + tid]);
            cthr[l][c] = ((DM - th) >> 1) + 1;
        }

    if (role == 1 && tid < 2 * VOCAB) hbL[tid] = hb[tid];

    double lacc0 = 0.0, lacc1 = 0.0;
    const int r0 = 2 * g;

    if (role == 0) {
        // ------------------------- stage A: layers 0-2 -------------------------
        for (int t = 0; t < TSTEPS; ++t) {
#pragma unroll
            for (int ri = 0; ri < 2; ++ri) {
                const int r = r0 + ri;
                if (t == 0) {
#pragma unroll
                    for (int c = 0; c < 2; ++c) {
                        u64 m = __ballot(initial_lat[c * THR + tid] < 0.0f);
                        if (lane == 0) hx[0][c * 8 + wv] = m;
                    }
                } else {
                    wait_ge(&fB[r], (u32)t); // acquire: xbuf fresh
                    if (wv == 0 && lane < 16) hx[0][lane] = xbuf[r * 16 + lane];
                }
                __syncthreads();
                REG_PASS(0, 0, if (lane == 0) { hx[1][wv] = m0_; hx[1][8 + wv] = m1_; });
                REG_PASS(1, 1, if (lane == 0) { hx[0][wv] = m0_; hx[0][8 + wv] = m1_; });
                LDS_PASS(0,    if (lane == 0) { mbuf[r * 16 + wv] = m0_;
                                                mbuf[r * 16 + 8 + wv] = m1_; });
                if (tid == 0)
                    __hip_atomic_store(&fA[r], (u32)(t + 1), __ATOMIC_RELEASE,
                                       __HIP_MEMORY_SCOPE_AGENT);
            }
        }
    } else {
        // ---------------- stage B: layers 3-5 + head + splice ----------------
        for (int t = 0; t < TSTEPS; ++t) {
#pragma unroll
            for (int ri = 0; ri < 2; ++ri) {
                const int r = r0 + ri;
                wait_ge(&fA[r], (u32)(t + 1));
                const int tok = tokens[r * TSTEPS + t]; // uniform scalar load
                u64 enew = 0;
                if (wv == 0 && lane < 2) enew = eb[tok * 2 + lane]; // prefetch
                if (wv == 0 && lane < 16) hx[0][lane] = mbuf[r * 16 + lane];
                __syncthreads();
                REG_PASS(0, 0, if (lane == 0) { hx[1][wv] = m0_; hx[1][8 + wv] = m1_; });
                REG_PASS(1, 1, if (lane == 0) { hx[0][wv] = m0_; hx[0][8 + wv] = m1_; });
                LDS_PASS(0,    if (lane == 0) {
                                   hx[1][wv] = m0_; hx[1][8 + wv] = m1_; // for head
                                   xbuf[r * 16 + wv] = m0_;     // carry words 0..13
                                   if (wv < 6) xbuf[r * 16 + 8 + wv] = m1_; });
                // head + log-softmax + loss + embed splice (wave 0); h5 in hx[1]
                if (wv == 0) {
                    u64 ra = hx[1][14], rb = hx[1][15];
                    u64 h0a = hbL[lane * 2 + 0],        h0b = hbL[lane * 2 + 1];
                    u64 h1a = hbL[(lane + 64) * 2 + 0], h1b = hbL[(lane + 64) * 2 + 1];
                    int d0 = 128 - 2 * (__popcll(ra ^ h0a) + __popcll(rb ^ h0b));
                    int d1 = 128 - 2 * (__popcll(ra ^ h1a) + __popcll(rb ^ h1b));
                    float l0 = (float)d0 * (1.0f / 16.0f);
                    float l1 = (float)d1 * (1.0f / 16.0f);
                    float mx = fmaxf(l0, l1);
#pragma unroll
                    for (int s = 32; s >= 1; s >>= 1) mx = fmaxf(mx, __shfl_xor(mx, s));
                    float se = __expf(l0 - mx) + __expf(l1 - mx);
#pragma unroll
                    for (int s = 32; s >= 1; s >>= 1) se += __shfl_xor(se, s);
                    int   tl   = tok & 63;
                    float la   = __shfl(l0, tl);
                    float lb_  = __shfl(l1, tl);
                    float ltok = (tok >> 6) ? lb_ : la;
                    double dl = (double)(mx + __logf(se) - ltok);
                    if (ri == 0) lacc0 += dl; else lacc1 += dl;
                    if (lane < 2) xbuf[r * 16 + 14 + lane] = enew; // read-part splice
                }
                __syncthreads(); // drain wave0's xbuf stores before release
                if (tid == 0)
                    __hip_atomic_store(&fB[r], (u32)(t + 1), __ATOMIC_RELEASE,
                                       __HIP_MEMORY_SCOPE_AGENT);
            }
        }
        if (tid == 0) { losses[r0] = lacc0; losses[r0 + 1] = lacc1; }
    }
}

__global__ void reduce_loss(const double* __restrict__ losses, float* __restrict__ out) {
    int lane = threadIdx.x; // 64 threads, 1 wave
    double v = losses[lane];
#pragma unroll
    for (int s = 32; s >= 1; s >>= 1) v += __shfl_down(v, s);
    if (lane == 0) out[0] = (float)(v * (1.0 / ((double)BATCH * (double)TSTEPS)));
}

extern "C" void kernel_launch(void* const* d_in, const int* in_sizes, int n_in,
                              void* d_out, int out_size, void* d_ws, size_t ws_size,
                              hipStream_t stream) {
    const int*   tokens  = (const int*)d_in[0];   // (64, 512) int32
    const float* initial = (const float*)d_in[1]; // (1024,)
    const float* embed   = (const float*)d_in[2]; // (128, 128)
    const float* ff      = (const float*)d_in[3]; // (6, 1024, 1024)
    const float* head    = (const float*)d_in[4]; // (128, 128)
    const float* thrl    = (const float*)d_in[5]; // (6, 1024)

    char* ws = (char*)d_ws;
    u64*    ffb    = (u64*)ws;
    u64*    eb     = (u64*)(ws + OFF_EB);
    u64*    hb     = (u64*)(ws + OFF_HB);
    double* losses = (double*)(ws + OFF_LOSS);
    u64*    xbuf   = (u64*)(ws + OFF_XBUF);
    u64*    mbuf   = (u64*)(ws + OFF_MBUF);
    u32*    fAf    = (u32*)(ws + OFF_FA);
    u32*    fBf    = (u32*)(ws + OFF_FB);

    // reset handshake flags every call (harness does not re-poison ws)
    hipMemsetAsync(ws + OFF_FA, 0, 512, stream);

    pack_ff<<<384, 256, 0, stream>>>(ff, ffb);
    pack_small<<<1, 256, 0, stream>>>(embed, head, eb, hb);
    brnn_pipe<<<BATCH, THR, 0, stream>>>(tokens, initial, thrl, ffb, eb, hb,
                                         xbuf, mbuf, fAf, fBf, losses);
    reduce_loss<<<1, 64, 0, stream>>>(losses, (float*)d_out);
}